// Round 9
// baseline (182.442 us; speedup 1.0000x reference)
//
#include <hip/hip_runtime.h>
#include <math.h>

#define S_LEN 2048
#define E_DIM 512
#define NE (S_LEN * E_DIM)
#define H_NUM 8
#define WH 32
#define NOFF 65
#define PROW (H_NUM * NOFF) /* 520 */
#define PN (S_LEN * PROW)

typedef float f32x4 __attribute__((ext_vector_type(4)));
typedef short short8 __attribute__((ext_vector_type(8)));

__device__ __forceinline__ unsigned short f2bf(float f) {
    union { float f; unsigned u; } cv; cv.f = f;
    unsigned u = cv.u;
    u += 0x7fffu + ((u >> 16) & 1u);   // RNE
    return (unsigned short)(u >> 16);
}
__device__ __forceinline__ unsigned pk2(float x, float y) {
    return (unsigned)f2bf(x) | ((unsigned)f2bf(y) << 16);
}
__device__ __forceinline__ float bf2f(unsigned short s) {
    union { unsigned u; float f; } cv; cv.u = ((unsigned)s) << 16;
    return cv.f;
}

// ---------------------------------------------------------------------------
// qkv (proven R3): C = (x@W + bias)*scale, in-kernel bf16 cast, 64x64 tiles.
// ---------------------------------------------------------------------------
__device__ __forceinline__ void mfma_gemm_f32(
    const float* __restrict__ A, const float* __restrict__ W,
    const float* __restrict__ bias, float* __restrict__ C,
    float scale, int m0, int n0)
{
    __shared__ unsigned short As[64 * 40];
    __shared__ unsigned short Bs[64 * 40];
    const int tid = threadIdx.x;
    const int lane = tid & 63, wave = tid >> 6;
    const int quad = lane >> 4, l16 = lane & 15;
    const int wr = (wave >> 1) * 32, wc = (wave & 1) * 32;
    const int ar = tid >> 2, ac = (tid & 3) * 8;
    const int bn = tid & 63, bk0 = (tid >> 6) * 8;

    f32x4 acc00 = {0.f,0.f,0.f,0.f}, acc01 = acc00, acc10 = acc00, acc11 = acc00;

    for (int kk = 0; kk < E_DIM; kk += 32) {
        float4 a0 = *(const float4*)(A + (size_t)(m0 + ar) * E_DIM + kk + ac);
        float4 a1 = *(const float4*)(A + (size_t)(m0 + ar) * E_DIM + kk + ac + 4);
        float b[8];
#pragma unroll
        for (int j = 0; j < 8; ++j)
            b[j] = W[(size_t)(kk + bk0 + j) * E_DIM + n0 + bn];
        __syncthreads();
        uint4 ap; ap.x = pk2(a0.x, a0.y); ap.y = pk2(a0.z, a0.w);
        ap.z = pk2(a1.x, a1.y); ap.w = pk2(a1.z, a1.w);
        *(uint4*)(As + ar * 40 + ac) = ap;
        uint4 bp; bp.x = pk2(b[0], b[1]); bp.y = pk2(b[2], b[3]);
        bp.z = pk2(b[4], b[5]); bp.w = pk2(b[6], b[7]);
        *(uint4*)(Bs + bn * 40 + bk0) = bp;
        __syncthreads();
        short8 fa0 = *(const short8*)(As + (wr + l16) * 40 + quad * 8);
        short8 fa1 = *(const short8*)(As + (wr + 16 + l16) * 40 + quad * 8);
        short8 fb0 = *(const short8*)(Bs + (wc + l16) * 40 + quad * 8);
        short8 fb1 = *(const short8*)(Bs + (wc + 16 + l16) * 40 + quad * 8);
        acc00 = __builtin_amdgcn_mfma_f32_16x16x32_bf16(fa0, fb0, acc00, 0, 0, 0);
        acc01 = __builtin_amdgcn_mfma_f32_16x16x32_bf16(fa0, fb1, acc01, 0, 0, 0);
        acc10 = __builtin_amdgcn_mfma_f32_16x16x32_bf16(fa1, fb0, acc10, 0, 0, 0);
        acc11 = __builtin_amdgcn_mfma_f32_16x16x32_bf16(fa1, fb1, acc11, 0, 0, 0);
    }

#pragma unroll
    for (int mi = 0; mi < 2; ++mi) {
#pragma unroll
        for (int ni = 0; ni < 2; ++ni) {
            f32x4 a = (mi == 0) ? ((ni == 0) ? acc00 : acc01)
                                : ((ni == 0) ? acc10 : acc11);
            int n = n0 + wc + ni * 16 + l16;
            float bval = bias[n];
#pragma unroll
            for (int r = 0; r < 4; ++r) {
                int m = m0 + wr + mi * 16 + quad * 4 + r;
                C[(size_t)m * E_DIM + n] = (a[r] + bval) * scale;
            }
        }
    }
}

__global__ __launch_bounds__(256)
void qkv_gemm(const float* __restrict__ x,
              const float* __restrict__ Wq, const float* __restrict__ bq,
              const float* __restrict__ Wk, const float* __restrict__ bk,
              const float* __restrict__ Wv, const float* __restrict__ bv,
              float* __restrict__ q, float* __restrict__ k, float* __restrict__ v)
{
    const float* W; const float* b; float* o; float sc;
    if (blockIdx.z == 0)      { W = Wq; b = bq; o = q; sc = 0.125f; }
    else if (blockIdx.z == 1) { W = Wk; b = bk; o = k; sc = 1.0f; }
    else                      { W = Wv; b = bv; o = v; sc = 1.0f; }
    mfma_gemm_f32(x, W, b, o, sc, blockIdx.y * 64, blockIdx.x * 64);
}

// ---------------------------------------------------------------------------
// scores_d1 (proven R8): scores + edge-softmax + diffusion step 1, fused.
// ---------------------------------------------------------------------------
#define SDN 32
__global__ __launch_bounds__(256)
void scores_d1(const float* __restrict__ q, const float* __restrict__ k,
               const float* __restrict__ v, const float* __restrict__ amask,
               float* __restrict__ P, float* __restrict__ hA)
{
    const int i0 = blockIdx.x * SDN;
    const int h  = blockIdx.y;
    const int tid = threadIdx.x;
    __shared__ float ks[96 * 68];      // k rows [i0-32,i0+64); later v rows
    __shared__ float am[96];
    __shared__ float sc[SDN * 66];
    __shared__ float smx[SDN], sidn[SDN];
    __shared__ float ps[SDN * NOFF];

    for (int e = tid; e < 96 * 16; e += 256) {
        int lr = e >> 4, c4 = e & 15;
        int j = i0 - WH + lr;
        int jc = min(max(j, 0), S_LEN - 1);
        *(float4*)(ks + lr * 68 + c4 * 4) =
            *(const float4*)(k + (size_t)jc * E_DIM + h * 64 + c4 * 4);
    }
    if (tid < 96) {
        int j = i0 - WH + tid;
        am[tid] = (j >= 0 && j < S_LEN) ? amask[j] : -1.0f;
    }

    const int dst = tid >> 3;
    const int og  = tid & 7;
    float4 qreg[16];
    {
        const float4* qrow = (const float4*)(q + (size_t)(i0 + dst) * E_DIM + h * 64);
#pragma unroll
        for (int t = 0; t < 16; ++t) qreg[t] = qrow[t];
    }
    __syncthreads();

    for (int off = og; off < NOFF; off += 8) {
        int j = i0 + dst + off - WH;
        float s;
        if (j < 0 || j >= S_LEN) {
            s = -INFINITY;
        } else {
            int lr = dst + off;
            const float4* kr = (const float4*)(ks + lr * 68);
            float acc = 0.f;
#pragma unroll
            for (int t = 0; t < 16; ++t) {
                float4 a = qreg[t], bb = kr[t];
                acc += a.x * bb.x + a.y * bb.y + a.z * bb.z + a.w * bb.w;
            }
            s = (am[lr] >= 0.f) ? acc : -1e9f;
        }
        sc[dst * 66 + off] = s;
    }
    __syncthreads();   // sc done; ks no longer read as k

    // overwrite ks with v rows [i0-32, i0+64) while row stats compute
    for (int e = tid; e < 96 * 16; e += 256) {
        int lr = e >> 4, c4 = e & 15;
        int j = i0 - WH + lr;
        int jc = min(max(j, 0), S_LEN - 1);
        *(float4*)(ks + lr * 68 + c4 * 4) =
            *(const float4*)(v + (size_t)jc * E_DIM + h * 64 + c4 * 4);
    }
    if (tid < SDN) {
        float mx = -INFINITY;
        for (int o = 0; o < NOFF; ++o) mx = fmaxf(mx, sc[tid * 66 + o]);
        float dn = 0.f;
        for (int o = 0; o < NOFF; ++o) dn += expf(sc[tid * 66 + o] - mx);
        smx[tid] = mx; sidn[tid] = 1.f / dn;
    }
    __syncthreads();

    for (int e = tid; e < SDN * NOFF; e += 256) {
        int d = e / NOFF, off = e - d * NOFF;
        float pv = expf(sc[d * 66 + off] - smx[d]) * sidn[d];
        P[(size_t)(i0 + d) * PROW + h * NOFF + off] = pv;
        ps[e] = pv;
    }
    __syncthreads();

    // diffusion step 1 for out rows i0..i0+31, head cols h
    {
        const int ci = tid & 15;
        const int ob = (tid >> 4) * 2;
        float4 a0 = {0,0,0,0}, a1 = a0;
        for (int lr = ob; lr < ob + 66; ++lr) {
            float4 hval = *(const float4*)(ks + lr * 68 + ci * 4);
            int o0 = lr - ob;
            if (o0 <= 64) {
                float p = ps[ob * NOFF + o0];
                a0.x += p * hval.x; a0.y += p * hval.y; a0.z += p * hval.z; a0.w += p * hval.w;
            }
            int o1 = o0 - 1;
            if ((unsigned)o1 <= 64u) {
                float p = ps[(ob + 1) * NOFF + o1];
                a1.x += p * hval.x; a1.y += p * hval.y; a1.z += p * hval.z; a1.w += p * hval.w;
            }
        }
#pragma unroll
        for (int r = 0; r < 2; ++r) {
            float4 a = r ? a1 : a0;
            float4 vv = *(const float4*)(ks + (WH + ob + r) * 68 + ci * 4);
            float4 o;
            o.x = 0.9f * a.x + 0.1f * vv.x;
            o.y = 0.9f * a.y + 0.1f * vv.y;
            o.z = 0.9f * a.z + 0.1f * vv.z;
            o.w = 0.9f * a.w + 0.1f * vv.w;
            *(float4*)(hA + (size_t)(i0 + ob + r) * E_DIM + h * 64 + ci * 4) = o;
        }
    }
}

// ---------------------------------------------------------------------------
// diffuse2c v2: TWO steps, 32-col blocks, bf16 LDS staging (hs/h1/ps).
// LDS 40.4 KB -> >=2 (likely 3) blocks/CU; LDS read bytes halved vs fp32.
// bf16(0) == 0 so the off-band-P-zero halo invariant is preserved exactly.
// block = 64 out rows x 32 cols. grid (32, 16).
// ---------------------------------------------------------------------------
__global__ __launch_bounds__(512)
void diffuse2c(const float* __restrict__ hin, const float* __restrict__ v,
               const float* __restrict__ P, float* __restrict__ hout)
{
    const int i0 = blockIdx.x * 64;
    const int c0 = blockIdx.y * 32;
    const int h  = c0 >> 6;
    const int tid = threadIdx.x;
    __shared__ unsigned short hs[192 * 36];   // 13824 B, stride 72 B (8B-aligned)
    __shared__ unsigned short h1[128 * 36];   //  9216 B
    __shared__ unsigned short ps[128 * 68];   // 17408 B, stride 136 B (8B-aligned)

    for (int e = tid; e < 192 * 8; e += 512) {
        int lr = e >> 3, c4 = e & 7;
        int j = i0 - 64 + lr;
        int jc = min(max(j, 0), S_LEN - 1);
        float4 hv = *(const float4*)(hin + (size_t)jc * E_DIM + c0 + c4 * 4);
        uint2 p; p.x = pk2(hv.x, hv.y); p.y = pk2(hv.z, hv.w);
        *(uint2*)(hs + lr * 36 + c4 * 4) = p;
    }
    // P staging: 128 rows x 65, vectorized 16x float4 + 1 tail
    for (int e = tid; e < 128 * 17; e += 512) {
        int mr = e / 17, t = e - mr * 17;
        int j = i0 - 32 + mr;
        int jc = min(max(j, 0), S_LEN - 1);
        const float* pr = P + (size_t)jc * PROW + h * NOFF;
        if (t < 16) {
            float4 pv = *(const float4*)(pr + t * 4);
            uint2 pp; pp.x = pk2(pv.x, pv.y); pp.y = pk2(pv.z, pv.w);
            *(uint2*)(ps + mr * 68 + t * 4) = pp;
        } else {
            ps[mr * 68 + 64] = f2bf(pr[64]);
        }
    }
    __syncthreads();

    const int ci = tid & 7;
    const int g  = tid >> 3;

    // ---- step A: mid rows g*2, g*2+1 ----
    {
        float4 a0 = {0,0,0,0}, a1 = a0;
        const int mb = g * 2;
        for (int lr = 0; lr < 66; ++lr) {
            ushort4 hv = *(const ushort4*)(hs + (mb + lr) * 36 + ci * 4);
            float hx = bf2f(hv.x), hy = bf2f(hv.y), hz = bf2f(hv.z), hw = bf2f(hv.w);
            if (lr <= 64) {
                float p = bf2f(ps[mb * 68 + lr]);
                a0.x += p * hx; a0.y += p * hy; a0.z += p * hz; a0.w += p * hw;
            }
            int o1 = lr - 1;
            if ((unsigned)o1 <= 64u) {
                float p = bf2f(ps[(mb + 1) * 68 + o1]);
                a1.x += p * hx; a1.y += p * hy; a1.z += p * hz; a1.w += p * hw;
            }
        }
#pragma unroll
        for (int r = 0; r < 2; ++r) {
            float4 a = r ? a1 : a0;
            int j = i0 - 32 + mb + r;
            int jc = min(max(j, 0), S_LEN - 1);
            float4 vv = *(const float4*)(v + (size_t)jc * E_DIM + c0 + ci * 4);
            float4 o;
            o.x = 0.9f * a.x + 0.1f * vv.x;
            o.y = 0.9f * a.y + 0.1f * vv.y;
            o.z = 0.9f * a.z + 0.1f * vv.z;
            o.w = 0.9f * a.w + 0.1f * vv.w;
            uint2 p; p.x = pk2(o.x, o.y); p.y = pk2(o.z, o.w);
            *(uint2*)(h1 + (mb + r) * 36 + ci * 4) = p;
        }
    }
    __syncthreads();

    // ---- step B: out row g ----
    {
        float4 a = {0,0,0,0};
        for (int off = 0; off < NOFF; ++off) {
            ushort4 hv = *(const ushort4*)(h1 + (g + off) * 36 + ci * 4);
            float p = bf2f(ps[(g + 32) * 68 + off]);
            a.x += p * bf2f(hv.x); a.y += p * bf2f(hv.y);
            a.z += p * bf2f(hv.z); a.w += p * bf2f(hv.w);
        }
        size_t base = (size_t)(i0 + g) * E_DIM + c0 + ci * 4;
        float4 vv = *(const float4*)(v + base);
        float4 o;
        o.x = 0.9f * a.x + 0.1f * vv.x;
        o.y = 0.9f * a.y + 0.1f * vv.y;
        o.z = 0.9f * a.z + 0.1f * vv.z;
        o.w = 0.9f * a.w + 0.1f * vv.w;
        *(float4*)(hout + base) = o;
    }
}

// ---------------------------------------------------------------------------
// oln (proven R4/R6): y = h@Wo + bo + x, then LayerNorm, fused.
// Block = 16 rows x 512 cols, 512 threads (8 waves x 4 n-tiles). 128 blocks.
// ---------------------------------------------------------------------------
__global__ __launch_bounds__(512)
void oln(const float* __restrict__ hsrc, const float* __restrict__ Wo,
         const float* __restrict__ bo, const float* __restrict__ x,
         const float* __restrict__ g, const float* __restrict__ lb,
         float* __restrict__ out)
{
    __shared__ unsigned short As[16 * 40];
    __shared__ unsigned short Bs[512 * 40];
    __shared__ float rsum[8][16], rsq[8][16];
    const int tid = threadIdx.x;
    const int lane = tid & 63, wave = tid >> 6;
    const int quad = lane >> 4, l16 = lane & 15;
    const int m0 = blockIdx.x * 16;
    const int n = tid;

    f32x4 acc[4];
#pragma unroll
    for (int t = 0; t < 4; ++t) acc[t] = (f32x4){0.f,0.f,0.f,0.f};

    for (int kk = 0; kk < E_DIM; kk += 32) {
        float4 av;
        if (tid < 128)
            av = *(const float4*)(hsrc + (size_t)(m0 + (tid >> 3)) * E_DIM + kk + (tid & 7) * 4);
        float bcol[32];
#pragma unroll
        for (int j = 0; j < 32; ++j)
            bcol[j] = Wo[(size_t)(kk + j) * E_DIM + n];
        __syncthreads();
        if (tid < 128) {
            uint2 ap; ap.x = pk2(av.x, av.y); ap.y = pk2(av.z, av.w);
            *(uint2*)(As + (tid >> 3) * 40 + (tid & 7) * 4) = ap;
        }
#pragma unroll
        for (int t = 0; t < 4; ++t) {
            uint4 bp;
            bp.x = pk2(bcol[t*8+0], bcol[t*8+1]); bp.y = pk2(bcol[t*8+2], bcol[t*8+3]);
            bp.z = pk2(bcol[t*8+4], bcol[t*8+5]); bp.w = pk2(bcol[t*8+6], bcol[t*8+7]);
            *(uint4*)(Bs + n * 40 + t * 8) = bp;
        }
        __syncthreads();
        short8 fa = *(const short8*)(As + l16 * 40 + quad * 8);
#pragma unroll
        for (int nt = 0; nt < 4; ++nt) {
            short8 fb = *(const short8*)(Bs + (wave * 64 + nt * 16 + l16) * 40 + quad * 8);
            acc[nt] = __builtin_amdgcn_mfma_f32_16x16x32_bf16(fa, fb, acc[nt], 0, 0, 0);
        }
    }

    float s[4] = {0.f,0.f,0.f,0.f}, s2[4] = {0.f,0.f,0.f,0.f};
#pragma unroll
    for (int nt = 0; nt < 4; ++nt) {
        int nc = wave * 64 + nt * 16 + l16;
        float bv = bo[nc];
#pragma unroll
        for (int r = 0; r < 4; ++r) {
            int m = m0 + quad * 4 + r;
            float vl = acc[nt][r] + bv + x[(size_t)m * E_DIM + nc];
            acc[nt][r] = vl;
            s[r] += vl; s2[r] += vl * vl;
        }
    }
#pragma unroll
    for (int o = 1; o < 16; o <<= 1) {
#pragma unroll
        for (int r = 0; r < 4; ++r) {
            s[r]  += __shfl_xor(s[r], o, 64);
            s2[r] += __shfl_xor(s2[r], o, 64);
        }
    }
    if (l16 == 0) {
#pragma unroll
        for (int r = 0; r < 4; ++r) {
            rsum[wave][quad * 4 + r] = s[r];
            rsq[wave][quad * 4 + r]  = s2[r];
        }
    }
    __syncthreads();
    float mu[4], rs[4];
#pragma unroll
    for (int r = 0; r < 4; ++r) {
        int rl = quad * 4 + r;
        float tot = 0.f, tot2 = 0.f;
#pragma unroll
        for (int w = 0; w < 8; ++w) { tot += rsum[w][rl]; tot2 += rsq[w][rl]; }
        float m_ = tot * (1.f / 512.f);
        float var = tot2 * (1.f / 512.f) - m_ * m_;
        mu[r] = m_; rs[r] = rsqrtf(var + 1e-12f);
    }
#pragma unroll
    for (int nt = 0; nt < 4; ++nt) {
        int nc = wave * 64 + nt * 16 + l16;
        float gv = g[nc], bbv = lb[nc];
#pragma unroll
        for (int r = 0; r < 4; ++r) {
            int m = m0 + quad * 4 + r;
            out[(size_t)m * E_DIM + nc] = (acc[nt][r] - mu[r]) * rs[r] * gv + bbv;
        }
    }
}

// ---------------------------------------------------------------------------
extern "C" void kernel_launch(void* const* d_in, const int* in_sizes, int n_in,
                              void* d_out, int out_size, void* d_ws, size_t ws_size,
                              hipStream_t stream)
{
    const float* x     = (const float*)d_in[0];
    const float* amask = (const float*)d_in[1];
    const float* Wq = (const float*)d_in[4];
    const float* bq = (const float*)d_in[5];
    const float* Wk = (const float*)d_in[6];
    const float* bk = (const float*)d_in[7];
    const float* Wv = (const float*)d_in[8];
    const float* bv = (const float*)d_in[9];
    const float* Wo = (const float*)d_in[10];
    const float* bo = (const float*)d_in[11];
    const float* lng = (const float*)d_in[12];
    const float* lnb = (const float*)d_in[13];
    float* out = (float*)d_out;

    float* ws = (float*)d_ws;
    float* q  = ws;
    float* k  = ws + (size_t)NE;
    float* v  = ws + (size_t)2 * NE;
    float* P  = ws + (size_t)3 * NE;
    float* hA = ws + (size_t)3 * NE + PN;
    float* hB = hA + (size_t)NE;

    qkv_gemm<<<dim3(8, 32, 3), 256, 0, stream>>>(x, Wq, bq, Wk, bk, Wv, bv, q, k, v);

    scores_d1<<<dim3(64, 8), 256, 0, stream>>>(q, k, v, amask, P, hA);  // P + step 1

    diffuse2c<<<dim3(32, 16), 512, 0, stream>>>(hA, v, P, hB);  // steps 2-3
    diffuse2c<<<dim3(32, 16), 512, 0, stream>>>(hB, v, P, hA);  // steps 4-5

    oln<<<128, 512, 0, stream>>>(hA, Wo, bo, x, lng, lnb, out);
}

// Round 10
// 175.640 us; speedup vs baseline: 1.0387x; 1.0387x over previous
//
#include <hip/hip_runtime.h>
#include <math.h>

#define S_LEN 2048
#define E_DIM 512
#define NE (S_LEN * E_DIM)
#define H_NUM 8
#define WH 32
#define NOFF 65
#define PROW (H_NUM * NOFF) /* 520 */
#define PN (S_LEN * PROW)

typedef float f32x4 __attribute__((ext_vector_type(4)));
typedef short short8 __attribute__((ext_vector_type(8)));

__device__ __forceinline__ unsigned short f2bf(float f) {
    union { float f; unsigned u; } cv; cv.f = f;
    unsigned u = cv.u;
    u += 0x7fffu + ((u >> 16) & 1u);   // RNE
    return (unsigned short)(u >> 16);
}
__device__ __forceinline__ unsigned pk2(float x, float y) {
    return (unsigned)f2bf(x) | ((unsigned)f2bf(y) << 16);
}

// ---------------------------------------------------------------------------
// qkv (proven R3/R8): C = (x@W + bias)*scale, in-kernel bf16 cast, 64x64 tiles.
// ---------------------------------------------------------------------------
__device__ __forceinline__ void mfma_gemm_f32(
    const float* __restrict__ A, const float* __restrict__ W,
    const float* __restrict__ bias, float* __restrict__ C,
    float scale, int m0, int n0)
{
    __shared__ unsigned short As[64 * 40];
    __shared__ unsigned short Bs[64 * 40];
    const int tid = threadIdx.x;
    const int lane = tid & 63, wave = tid >> 6;
    const int quad = lane >> 4, l16 = lane & 15;
    const int wr = (wave >> 1) * 32, wc = (wave & 1) * 32;
    const int ar = tid >> 2, ac = (tid & 3) * 8;
    const int bn = tid & 63, bk0 = (tid >> 6) * 8;

    f32x4 acc00 = {0.f,0.f,0.f,0.f}, acc01 = acc00, acc10 = acc00, acc11 = acc00;

    for (int kk = 0; kk < E_DIM; kk += 32) {
        float4 a0 = *(const float4*)(A + (size_t)(m0 + ar) * E_DIM + kk + ac);
        float4 a1 = *(const float4*)(A + (size_t)(m0 + ar) * E_DIM + kk + ac + 4);
        float b[8];
#pragma unroll
        for (int j = 0; j < 8; ++j)
            b[j] = W[(size_t)(kk + bk0 + j) * E_DIM + n0 + bn];
        __syncthreads();
        uint4 ap; ap.x = pk2(a0.x, a0.y); ap.y = pk2(a0.z, a0.w);
        ap.z = pk2(a1.x, a1.y); ap.w = pk2(a1.z, a1.w);
        *(uint4*)(As + ar * 40 + ac) = ap;
        uint4 bp; bp.x = pk2(b[0], b[1]); bp.y = pk2(b[2], b[3]);
        bp.z = pk2(b[4], b[5]); bp.w = pk2(b[6], b[7]);
        *(uint4*)(Bs + bn * 40 + bk0) = bp;
        __syncthreads();
        short8 fa0 = *(const short8*)(As + (wr + l16) * 40 + quad * 8);
        short8 fa1 = *(const short8*)(As + (wr + 16 + l16) * 40 + quad * 8);
        short8 fb0 = *(const short8*)(Bs + (wc + l16) * 40 + quad * 8);
        short8 fb1 = *(const short8*)(Bs + (wc + 16 + l16) * 40 + quad * 8);
        acc00 = __builtin_amdgcn_mfma_f32_16x16x32_bf16(fa0, fb0, acc00, 0, 0, 0);
        acc01 = __builtin_amdgcn_mfma_f32_16x16x32_bf16(fa0, fb1, acc01, 0, 0, 0);
        acc10 = __builtin_amdgcn_mfma_f32_16x16x32_bf16(fa1, fb0, acc10, 0, 0, 0);
        acc11 = __builtin_amdgcn_mfma_f32_16x16x32_bf16(fa1, fb1, acc11, 0, 0, 0);
    }

#pragma unroll
    for (int mi = 0; mi < 2; ++mi) {
#pragma unroll
        for (int ni = 0; ni < 2; ++ni) {
            f32x4 a = (mi == 0) ? ((ni == 0) ? acc00 : acc01)
                                : ((ni == 0) ? acc10 : acc11);
            int n = n0 + wc + ni * 16 + l16;
            float bval = bias[n];
#pragma unroll
            for (int r = 0; r < 4; ++r) {
                int m = m0 + wr + mi * 16 + quad * 4 + r;
                C[(size_t)m * E_DIM + n] = (a[r] + bval) * scale;
            }
        }
    }
}

__global__ __launch_bounds__(256)
void qkv_gemm(const float* __restrict__ x,
              const float* __restrict__ Wq, const float* __restrict__ bq,
              const float* __restrict__ Wk, const float* __restrict__ bk,
              const float* __restrict__ Wv, const float* __restrict__ bv,
              float* __restrict__ q, float* __restrict__ k, float* __restrict__ v)
{
    const float* W; const float* b; float* o; float sc;
    if (blockIdx.z == 0)      { W = Wq; b = bq; o = q; sc = 0.125f; }
    else if (blockIdx.z == 1) { W = Wk; b = bk; o = k; sc = 1.0f; }
    else                      { W = Wv; b = bv; o = v; sc = 1.0f; }
    mfma_gemm_f32(x, W, b, o, sc, blockIdx.y * 64, blockIdx.x * 64);
}

// ---------------------------------------------------------------------------
// scores_d1 (proven R8): scores + edge-softmax + diffusion step 1, fused.
// ---------------------------------------------------------------------------
#define SDN 32
__global__ __launch_bounds__(256)
void scores_d1(const float* __restrict__ q, const float* __restrict__ k,
               const float* __restrict__ v, const float* __restrict__ amask,
               float* __restrict__ P, float* __restrict__ hA)
{
    const int i0 = blockIdx.x * SDN;
    const int h  = blockIdx.y;
    const int tid = threadIdx.x;
    __shared__ float ks[96 * 68];      // k rows [i0-32,i0+64); later v rows
    __shared__ float am[96];
    __shared__ float sc[SDN * 66];
    __shared__ float smx[SDN], sidn[SDN];
    __shared__ float ps[SDN * NOFF];

    for (int e = tid; e < 96 * 16; e += 256) {
        int lr = e >> 4, c4 = e & 15;
        int j = i0 - WH + lr;
        int jc = min(max(j, 0), S_LEN - 1);
        *(float4*)(ks + lr * 68 + c4 * 4) =
            *(const float4*)(k + (size_t)jc * E_DIM + h * 64 + c4 * 4);
    }
    if (tid < 96) {
        int j = i0 - WH + tid;
        am[tid] = (j >= 0 && j < S_LEN) ? amask[j] : -1.0f;
    }

    const int dst = tid >> 3;
    const int og  = tid & 7;
    float4 qreg[16];
    {
        const float4* qrow = (const float4*)(q + (size_t)(i0 + dst) * E_DIM + h * 64);
#pragma unroll
        for (int t = 0; t < 16; ++t) qreg[t] = qrow[t];
    }
    __syncthreads();

    for (int off = og; off < NOFF; off += 8) {
        int j = i0 + dst + off - WH;
        float s;
        if (j < 0 || j >= S_LEN) {
            s = -INFINITY;
        } else {
            int lr = dst + off;
            const float4* kr = (const float4*)(ks + lr * 68);
            float acc = 0.f;
#pragma unroll
            for (int t = 0; t < 16; ++t) {
                float4 a = qreg[t], bb = kr[t];
                acc += a.x * bb.x + a.y * bb.y + a.z * bb.z + a.w * bb.w;
            }
            s = (am[lr] >= 0.f) ? acc : -1e9f;
        }
        sc[dst * 66 + off] = s;
    }
    __syncthreads();   // sc done; ks no longer read as k

    // overwrite ks with v rows [i0-32, i0+64) while row stats compute
    for (int e = tid; e < 96 * 16; e += 256) {
        int lr = e >> 4, c4 = e & 15;
        int j = i0 - WH + lr;
        int jc = min(max(j, 0), S_LEN - 1);
        *(float4*)(ks + lr * 68 + c4 * 4) =
            *(const float4*)(v + (size_t)jc * E_DIM + h * 64 + c4 * 4);
    }
    if (tid < SDN) {
        float mx = -INFINITY;
        for (int o = 0; o < NOFF; ++o) mx = fmaxf(mx, sc[tid * 66 + o]);
        float dn = 0.f;
        for (int o = 0; o < NOFF; ++o) dn += expf(sc[tid * 66 + o] - mx);
        smx[tid] = mx; sidn[tid] = 1.f / dn;
    }
    __syncthreads();

    for (int e = tid; e < SDN * NOFF; e += 256) {
        int d = e / NOFF, off = e - d * NOFF;
        float pv = expf(sc[d * 66 + off] - smx[d]) * sidn[d];
        P[(size_t)(i0 + d) * PROW + h * NOFF + off] = pv;
        ps[e] = pv;
    }
    __syncthreads();

    // diffusion step 1 for out rows i0..i0+31, head cols h
    {
        const int ci = tid & 15;
        const int ob = (tid >> 4) * 2;
        float4 a0 = {0,0,0,0}, a1 = a0;
        for (int lr = ob; lr < ob + 66; ++lr) {
            float4 hval = *(const float4*)(ks + lr * 68 + ci * 4);
            int o0 = lr - ob;
            if (o0 <= 64) {
                float p = ps[ob * NOFF + o0];
                a0.x += p * hval.x; a0.y += p * hval.y; a0.z += p * hval.z; a0.w += p * hval.w;
            }
            int o1 = o0 - 1;
            if ((unsigned)o1 <= 64u) {
                float p = ps[(ob + 1) * NOFF + o1];
                a1.x += p * hval.x; a1.y += p * hval.y; a1.z += p * hval.z; a1.w += p * hval.w;
            }
        }
#pragma unroll
        for (int r = 0; r < 2; ++r) {
            float4 a = r ? a1 : a0;
            float4 vv = *(const float4*)(ks + (WH + ob + r) * 68 + ci * 4);
            float4 o;
            o.x = 0.9f * a.x + 0.1f * vv.x;
            o.y = 0.9f * a.y + 0.1f * vv.y;
            o.z = 0.9f * a.z + 0.1f * vv.z;
            o.w = 0.9f * a.w + 0.1f * vv.w;
            *(float4*)(hA + (size_t)(i0 + ob + r) * E_DIM + h * 64 + ci * 4) = o;
        }
    }
}

// ---------------------------------------------------------------------------
// diffuse2m: TWO diffusion steps via banded MFMA. block = 64 out rows x 64
// cols (one head), 256 threads (4 waves). grid (32, 8).
//   step 1: mid[m=128] = P-band[128 x k192] @ hT[k192 x n64]   (MFMA)
//   step 2: out[m=64]  = P-band[64 x k128]  @ m1T[k128 x n64]  (MFMA)
// A-fragments built from compact ps[row][65] bf16 via masked u16 reads
// (off = k - m; off-band == exact 0 -> halo invariant preserved).
// h staged TRANSPOSED (hT[col][row]) so B-fragments are contiguous b128;
// step-1 output written transposed directly from MFMA C-layout (b64).
// LDS: hT 25600 + m1T 17408 + ps 17408 = 60.4 KB.
// ---------------------------------------------------------------------------
__global__ __launch_bounds__(256)
void diffuse2m(const float* __restrict__ hin, const float* __restrict__ v,
               const float* __restrict__ P, float* __restrict__ hout)
{
    __shared__ unsigned short hT[64 * 200];   // [col][in-row 0..191]
    __shared__ unsigned short m1T[64 * 136];  // [col][mid-row 0..127]
    __shared__ unsigned short ps[128 * 68];   // [mid-row][off 0..64]
    const int i0 = blockIdx.x * 64;
    const int h  = blockIdx.y;
    const int c0 = h * 64;
    const int tid  = threadIdx.x;
    const int lane = tid & 63, wave = tid >> 6;
    const int quad = lane >> 4, l16 = lane & 15;

    // ---- stage hT: in rows [i0-64, i0+128) -> bf16 transposed.
    // Two consecutive rows per iter so LDS writes are b32 (pair along row dim).
    for (int e = tid; e < 96 * 16; e += 256) {
        int lr2 = (e >> 4) * 2, c4 = (e & 15) * 4;
        int ja = min(max(i0 - 64 + lr2,     0), S_LEN - 1);
        int jb = min(max(i0 - 64 + lr2 + 1, 0), S_LEN - 1);
        float4 ha = *(const float4*)(hin + (size_t)ja * E_DIM + c0 + c4);
        float4 hb = *(const float4*)(hin + (size_t)jb * E_DIM + c0 + c4);
        *(unsigned*)(hT + (c4 + 0) * 200 + lr2) = pk2(ha.x, hb.x);
        *(unsigned*)(hT + (c4 + 1) * 200 + lr2) = pk2(ha.y, hb.y);
        *(unsigned*)(hT + (c4 + 2) * 200 + lr2) = pk2(ha.z, hb.z);
        *(unsigned*)(hT + (c4 + 3) * 200 + lr2) = pk2(ha.w, hb.w);
    }
    // ---- stage ps: mid rows [i0-32, i0+96), 65 offs as bf16 (b32-pair writes)
    for (int e = tid; e < 128 * 33; e += 256) {
        int mr = e / 33, t = e - mr * 33;
        int jc = min(max(i0 - 32 + mr, 0), S_LEN - 1);
        const float* pr = P + (size_t)jc * PROW + h * NOFF;
        if (t < 32) {
            *(unsigned*)(ps + mr * 68 + t * 2) = pk2(pr[t * 2], pr[t * 2 + 1]);
        } else {
            ps[mr * 68 + 64] = f2bf(pr[64]);
        }
    }
    __syncthreads();

    // ---- step 1: wave w computes mid rows [32w, 32w+32) (2 m-tiles), all 64 cols.
    const int mt0 = wave * 32;
    f32x4 acc1[2][4];
#pragma unroll
    for (int a = 0; a < 2; ++a)
#pragma unroll
        for (int b = 0; b < 4; ++b) acc1[a][b] = (f32x4){0.f,0.f,0.f,0.f};

    for (int ks = wave; ks <= wave + 2; ++ks) {    // valid k-window for both m-tiles
        const int k0q = ks * 32 + quad * 8;
        short8 fb[4];
#pragma unroll
        for (int nt = 0; nt < 4; ++nt)
            fb[nt] = *(const short8*)(hT + (nt * 16 + l16) * 200 + k0q);
#pragma unroll
        for (int mt = 0; mt < 2; ++mt) {
            const int m = mt0 + mt * 16 + l16;
            const int start = k0q - m;
            short8 fa;
#pragma unroll
            for (int j = 0; j < 8; ++j) {
                int idx = start + j;
                int idc = min(max(idx, 0), 64);
                unsigned short pv = ps[m * 68 + idc];
                fa[j] = ((unsigned)idx <= 64u) ? (short)pv : (short)0;
            }
#pragma unroll
            for (int nt = 0; nt < 4; ++nt)
                acc1[mt][nt] = __builtin_amdgcn_mfma_f32_16x16x32_bf16(fa, fb[nt], acc1[mt][nt], 0, 0, 0);
        }
    }

    // blend with v, write m1T transposed (C-layout: col=l16, rows quad*4+r)
#pragma unroll
    for (int mt = 0; mt < 2; ++mt) {
#pragma unroll
        for (int nt = 0; nt < 4; ++nt) {
            int n = nt * 16 + l16;
            int mbase = mt0 + mt * 16 + quad * 4;
            float o[4];
#pragma unroll
            for (int r = 0; r < 4; ++r) {
                int mgc = min(max(i0 - 32 + mbase + r, 0), S_LEN - 1);
                float vv = v[(size_t)mgc * E_DIM + c0 + n];
                o[r] = 0.9f * acc1[mt][nt][r] + 0.1f * vv;
            }
            uint2 pkd; pkd.x = pk2(o[0], o[1]); pkd.y = pk2(o[2], o[3]);
            *(uint2*)(m1T + n * 136 + mbase) = pkd;
        }
    }
    __syncthreads();

    // ---- step 2: wave w computes out rows [16w, 16w+16), all 64 cols.
    const int mt2 = wave * 16;
    f32x4 acc2[4];
#pragma unroll
    for (int b = 0; b < 4; ++b) acc2[b] = (f32x4){0.f,0.f,0.f,0.f};

    const int kslo = mt2 >> 5, kshi = (mt2 + 79) >> 5;
    for (int ks = kslo; ks <= kshi; ++ks) {
        const int k0q = ks * 32 + quad * 8;
        short8 fb[4];
#pragma unroll
        for (int nt = 0; nt < 4; ++nt)
            fb[nt] = *(const short8*)(m1T + (nt * 16 + l16) * 136 + k0q);
        const int m = mt2 + l16;
        const int start = k0q - m;
        short8 fa;
#pragma unroll
        for (int j = 0; j < 8; ++j) {
            int idx = start + j;
            int idc = min(max(idx, 0), 64);
            unsigned short pv = ps[(m + 32) * 68 + idc];
            fa[j] = ((unsigned)idx <= 64u) ? (short)pv : (short)0;
        }
#pragma unroll
        for (int nt = 0; nt < 4; ++nt)
            acc2[nt] = __builtin_amdgcn_mfma_f32_16x16x32_bf16(fa, fb[nt], acc2[nt], 0, 0, 0);
    }

    // blend + store out rows (coalesced 64B segments per quad)
#pragma unroll
    for (int nt = 0; nt < 4; ++nt) {
        int n = nt * 16 + l16;
#pragma unroll
        for (int r = 0; r < 4; ++r) {
            int m = mt2 + quad * 4 + r;
            size_t base = (size_t)(i0 + m) * E_DIM + c0 + n;
            hout[base] = 0.9f * acc2[nt][r] + 0.1f * v[base];
        }
    }
}

// ---------------------------------------------------------------------------
// oln (proven R4/R6/R8): y = h@Wo + bo + x, then LayerNorm, fused.
// ---------------------------------------------------------------------------
__global__ __launch_bounds__(512)
void oln(const float* __restrict__ hsrc, const float* __restrict__ Wo,
         const float* __restrict__ bo, const float* __restrict__ x,
         const float* __restrict__ g, const float* __restrict__ lb,
         float* __restrict__ out)
{
    __shared__ unsigned short As[16 * 40];
    __shared__ unsigned short Bs[512 * 40];
    __shared__ float rsum[8][16], rsq[8][16];
    const int tid = threadIdx.x;
    const int lane = tid & 63, wave = tid >> 6;
    const int quad = lane >> 4, l16 = lane & 15;
    const int m0 = blockIdx.x * 16;
    const int n = tid;

    f32x4 acc[4];
#pragma unroll
    for (int t = 0; t < 4; ++t) acc[t] = (f32x4){0.f,0.f,0.f,0.f};

    for (int kk = 0; kk < E_DIM; kk += 32) {
        float4 av;
        if (tid < 128)
            av = *(const float4*)(hsrc + (size_t)(m0 + (tid >> 3)) * E_DIM + kk + (tid & 7) * 4);
        float bcol[32];
#pragma unroll
        for (int j = 0; j < 32; ++j)
            bcol[j] = Wo[(size_t)(kk + j) * E_DIM + n];
        __syncthreads();
        if (tid < 128) {
            uint2 ap; ap.x = pk2(av.x, av.y); ap.y = pk2(av.z, av.w);
            *(uint2*)(As + (tid >> 3) * 40 + (tid & 7) * 4) = ap;
        }
#pragma unroll
        for (int t = 0; t < 4; ++t) {
            uint4 bp;
            bp.x = pk2(bcol[t*8+0], bcol[t*8+1]); bp.y = pk2(bcol[t*8+2], bcol[t*8+3]);
            bp.z = pk2(bcol[t*8+4], bcol[t*8+5]); bp.w = pk2(bcol[t*8+6], bcol[t*8+7]);
            *(uint4*)(Bs + n * 40 + t * 8) = bp;
        }
        __syncthreads();
        short8 fa = *(const short8*)(As + l16 * 40 + quad * 8);
#pragma unroll
        for (int nt = 0; nt < 4; ++nt) {
            short8 fb = *(const short8*)(Bs + (wave * 64 + nt * 16 + l16) * 40 + quad * 8);
            acc[nt] = __builtin_amdgcn_mfma_f32_16x16x32_bf16(fa, fb, acc[nt], 0, 0, 0);
        }
    }

    float s[4] = {0.f,0.f,0.f,0.f}, s2[4] = {0.f,0.f,0.f,0.f};
#pragma unroll
    for (int nt = 0; nt < 4; ++nt) {
        int nc = wave * 64 + nt * 16 + l16;
        float bv = bo[nc];
#pragma unroll
        for (int r = 0; r < 4; ++r) {
            int m = m0 + quad * 4 + r;
            float vl = acc[nt][r] + bv + x[(size_t)m * E_DIM + nc];
            acc[nt][r] = vl;
            s[r] += vl; s2[r] += vl * vl;
        }
    }
#pragma unroll
    for (int o = 1; o < 16; o <<= 1) {
#pragma unroll
        for (int r = 0; r < 4; ++r) {
            s[r]  += __shfl_xor(s[r], o, 64);
            s2[r] += __shfl_xor(s2[r], o, 64);
        }
    }
    if (l16 == 0) {
#pragma unroll
        for (int r = 0; r < 4; ++r) {
            rsum[wave][quad * 4 + r] = s[r];
            rsq[wave][quad * 4 + r]  = s2[r];
        }
    }
    __syncthreads();
    float mu[4], rs[4];
#pragma unroll
    for (int r = 0; r < 4; ++r) {
        int rl = quad * 4 + r;
        float tot = 0.f, tot2 = 0.f;
#pragma unroll
        for (int w = 0; w < 8; ++w) { tot += rsum[w][rl]; tot2 += rsq[w][rl]; }
        float m_ = tot * (1.f / 512.f);
        float var = tot2 * (1.f / 512.f) - m_ * m_;
        mu[r] = m_; rs[r] = rsqrtf(var + 1e-12f);
    }
#pragma unroll
    for (int nt = 0; nt < 4; ++nt) {
        int nc = wave * 64 + nt * 16 + l16;
        float gv = g[nc], bbv = lb[nc];
#pragma unroll
        for (int r = 0; r < 4; ++r) {
            int m = m0 + quad * 4 + r;
            out[(size_t)m * E_DIM + nc] = (acc[nt][r] - mu[r]) * rs[r] * gv + bbv;
        }
    }
}

// ---------------------------------------------------------------------------
extern "C" void kernel_launch(void* const* d_in, const int* in_sizes, int n_in,
                              void* d_out, int out_size, void* d_ws, size_t ws_size,
                              hipStream_t stream)
{
    const float* x     = (const float*)d_in[0];
    const float* amask = (const float*)d_in[1];
    const float* Wq = (const float*)d_in[4];
    const float* bq = (const float*)d_in[5];
    const float* Wk = (const float*)d_in[6];
    const float* bk = (const float*)d_in[7];
    const float* Wv = (const float*)d_in[8];
    const float* bv = (const float*)d_in[9];
    const float* Wo = (const float*)d_in[10];
    const float* bo = (const float*)d_in[11];
    const float* lng = (const float*)d_in[12];
    const float* lnb = (const float*)d_in[13];
    float* out = (float*)d_out;

    float* ws = (float*)d_ws;
    float* q  = ws;
    float* k  = ws + (size_t)NE;
    float* v  = ws + (size_t)2 * NE;
    float* P  = ws + (size_t)3 * NE;
    float* hA = ws + (size_t)3 * NE + PN;
    float* hB = hA + (size_t)NE;

    qkv_gemm<<<dim3(8, 32, 3), 256, 0, stream>>>(x, Wq, bq, Wk, bk, Wv, bv, q, k, v);

    scores_d1<<<dim3(64, 8), 256, 0, stream>>>(q, k, v, amask, P, hA);  // P + step 1

    diffuse2m<<<dim3(32, 8), 256, 0, stream>>>(hA, v, P, hB);  // steps 2-3 (MFMA)
    diffuse2m<<<dim3(32, 8), 256, 0, stream>>>(hB, v, P, hA);  // steps 4-5 (MFMA)

    oln<<<128, 512, 0, stream>>>(hA, Wo, bo, x, lng, lnb, out);
}

// Round 12
// 172.657 us; speedup vs baseline: 1.0567x; 1.0173x over previous
//
#include <hip/hip_runtime.h>
#include <math.h>

#define S_LEN 2048
#define E_DIM 512
#define NE (S_LEN * E_DIM)
#define H_NUM 8
#define WH 32
#define NOFF 65
#define PROW (H_NUM * NOFF) /* 520 */
#define PN (S_LEN * PROW)

typedef float f32x4 __attribute__((ext_vector_type(4)));
typedef short short8 __attribute__((ext_vector_type(8)));

__device__ __forceinline__ unsigned short f2bf(float f) {
    union { float f; unsigned u; } cv; cv.f = f;
    unsigned u = cv.u;
    u += 0x7fffu + ((u >> 16) & 1u);   // RNE
    return (unsigned short)(u >> 16);
}
__device__ __forceinline__ unsigned pk2(float x, float y) {
    return (unsigned)f2bf(x) | ((unsigned)f2bf(y) << 16);
}

// ---------------------------------------------------------------------------
// qkv (proven R3/R8): C = (x@W + bias)*scale, in-kernel bf16 cast, 64x64 tiles.
// ---------------------------------------------------------------------------
__device__ __forceinline__ void mfma_gemm_f32(
    const float* __restrict__ A, const float* __restrict__ W,
    const float* __restrict__ bias, float* __restrict__ C,
    float scale, int m0, int n0)
{
    __shared__ unsigned short As[64 * 40];
    __shared__ unsigned short Bs[64 * 40];
    const int tid = threadIdx.x;
    const int lane = tid & 63, wave = tid >> 6;
    const int quad = lane >> 4, l16 = lane & 15;
    const int wr = (wave >> 1) * 32, wc = (wave & 1) * 32;
    const int ar = tid >> 2, ac = (tid & 3) * 8;
    const int bn = tid & 63, bk0 = (tid >> 6) * 8;

    f32x4 acc00 = {0.f,0.f,0.f,0.f}, acc01 = acc00, acc10 = acc00, acc11 = acc00;

    for (int kk = 0; kk < E_DIM; kk += 32) {
        float4 a0 = *(const float4*)(A + (size_t)(m0 + ar) * E_DIM + kk + ac);
        float4 a1 = *(const float4*)(A + (size_t)(m0 + ar) * E_DIM + kk + ac + 4);
        float b[8];
#pragma unroll
        for (int j = 0; j < 8; ++j)
            b[j] = W[(size_t)(kk + bk0 + j) * E_DIM + n0 + bn];
        __syncthreads();
        uint4 ap; ap.x = pk2(a0.x, a0.y); ap.y = pk2(a0.z, a0.w);
        ap.z = pk2(a1.x, a1.y); ap.w = pk2(a1.z, a1.w);
        *(uint4*)(As + ar * 40 + ac) = ap;
        uint4 bp; bp.x = pk2(b[0], b[1]); bp.y = pk2(b[2], b[3]);
        bp.z = pk2(b[4], b[5]); bp.w = pk2(b[6], b[7]);
        *(uint4*)(Bs + bn * 40 + bk0) = bp;
        __syncthreads();
        short8 fa0 = *(const short8*)(As + (wr + l16) * 40 + quad * 8);
        short8 fa1 = *(const short8*)(As + (wr + 16 + l16) * 40 + quad * 8);
        short8 fb0 = *(const short8*)(Bs + (wc + l16) * 40 + quad * 8);
        short8 fb1 = *(const short8*)(Bs + (wc + 16 + l16) * 40 + quad * 8);
        acc00 = __builtin_amdgcn_mfma_f32_16x16x32_bf16(fa0, fb0, acc00, 0, 0, 0);
        acc01 = __builtin_amdgcn_mfma_f32_16x16x32_bf16(fa0, fb1, acc01, 0, 0, 0);
        acc10 = __builtin_amdgcn_mfma_f32_16x16x32_bf16(fa1, fb0, acc10, 0, 0, 0);
        acc11 = __builtin_amdgcn_mfma_f32_16x16x32_bf16(fa1, fb1, acc11, 0, 0, 0);
    }

#pragma unroll
    for (int mi = 0; mi < 2; ++mi) {
#pragma unroll
        for (int ni = 0; ni < 2; ++ni) {
            f32x4 a = (mi == 0) ? ((ni == 0) ? acc00 : acc01)
                                : ((ni == 0) ? acc10 : acc11);
            int n = n0 + wc + ni * 16 + l16;
            float bval = bias[n];
#pragma unroll
            for (int r = 0; r < 4; ++r) {
                int m = m0 + wr + mi * 16 + quad * 4 + r;
                C[(size_t)m * E_DIM + n] = (a[r] + bval) * scale;
            }
        }
    }
}

__global__ __launch_bounds__(256)
void qkv_gemm(const float* __restrict__ x,
              const float* __restrict__ Wq, const float* __restrict__ bq,
              const float* __restrict__ Wk, const float* __restrict__ bk,
              const float* __restrict__ Wv, const float* __restrict__ bv,
              float* __restrict__ q, float* __restrict__ k, float* __restrict__ v)
{
    const float* W; const float* b; float* o; float sc;
    if (blockIdx.z == 0)      { W = Wq; b = bq; o = q; sc = 0.125f; }
    else if (blockIdx.z == 1) { W = Wk; b = bk; o = k; sc = 1.0f; }
    else                      { W = Wv; b = bv; o = v; sc = 1.0f; }
    mfma_gemm_f32(x, W, b, o, sc, blockIdx.y * 64, blockIdx.x * 64);
}

// ---------------------------------------------------------------------------
// scores_d1 (proven R8): scores + edge-softmax + diffusion step 1, fused.
// ---------------------------------------------------------------------------
#define SDN 32
__global__ __launch_bounds__(256)
void scores_d1(const float* __restrict__ q, const float* __restrict__ k,
               const float* __restrict__ v, const float* __restrict__ amask,
               float* __restrict__ P, float* __restrict__ hA)
{
    const int i0 = blockIdx.x * SDN;
    const int h  = blockIdx.y;
    const int tid = threadIdx.x;
    __shared__ float ks[96 * 68];      // k rows [i0-32,i0+64); later v rows
    __shared__ float am[96];
    __shared__ float sc[SDN * 66];
    __shared__ float smx[SDN], sidn[SDN];
    __shared__ float ps[SDN * NOFF];

    for (int e = tid; e < 96 * 16; e += 256) {
        int lr = e >> 4, c4 = e & 15;
        int j = i0 - WH + lr;
        int jc = min(max(j, 0), S_LEN - 1);
        *(float4*)(ks + lr * 68 + c4 * 4) =
            *(const float4*)(k + (size_t)jc * E_DIM + h * 64 + c4 * 4);
    }
    if (tid < 96) {
        int j = i0 - WH + tid;
        am[tid] = (j >= 0 && j < S_LEN) ? amask[j] : -1.0f;
    }

    const int dst = tid >> 3;
    const int og  = tid & 7;
    float4 qreg[16];
    {
        const float4* qrow = (const float4*)(q + (size_t)(i0 + dst) * E_DIM + h * 64);
#pragma unroll
        for (int t = 0; t < 16; ++t) qreg[t] = qrow[t];
    }
    __syncthreads();

    for (int off = og; off < NOFF; off += 8) {
        int j = i0 + dst + off - WH;
        float s;
        if (j < 0 || j >= S_LEN) {
            s = -INFINITY;
        } else {
            int lr = dst + off;
            const float4* kr = (const float4*)(ks + lr * 68);
            float acc = 0.f;
#pragma unroll
            for (int t = 0; t < 16; ++t) {
                float4 a = qreg[t], bb = kr[t];
                acc += a.x * bb.x + a.y * bb.y + a.z * bb.z + a.w * bb.w;
            }
            s = (am[lr] >= 0.f) ? acc : -1e9f;
        }
        sc[dst * 66 + off] = s;
    }
    __syncthreads();   // sc done; ks no longer read as k

    for (int e = tid; e < 96 * 16; e += 256) {
        int lr = e >> 4, c4 = e & 15;
        int j = i0 - WH + lr;
        int jc = min(max(j, 0), S_LEN - 1);
        *(float4*)(ks + lr * 68 + c4 * 4) =
            *(const float4*)(v + (size_t)jc * E_DIM + h * 64 + c4 * 4);
    }
    if (tid < SDN) {
        float mx = -INFINITY;
        for (int o = 0; o < NOFF; ++o) mx = fmaxf(mx, sc[tid * 66 + o]);
        float dn = 0.f;
        for (int o = 0; o < NOFF; ++o) dn += expf(sc[tid * 66 + o] - mx);
        smx[tid] = mx; sidn[tid] = 1.f / dn;
    }
    __syncthreads();

    for (int e = tid; e < SDN * NOFF; e += 256) {
        int d = e / NOFF, off = e - d * NOFF;
        float pv = expf(sc[d * 66 + off] - smx[d]) * sidn[d];
        P[(size_t)(i0 + d) * PROW + h * NOFF + off] = pv;
        ps[e] = pv;
    }
    __syncthreads();

    {
        const int ci = tid & 15;
        const int ob = (tid >> 4) * 2;
        float4 a0 = {0,0,0,0}, a1 = a0;
        for (int lr = ob; lr < ob + 66; ++lr) {
            float4 hval = *(const float4*)(ks + lr * 68 + ci * 4);
            int o0 = lr - ob;
            if (o0 <= 64) {
                float p = ps[ob * NOFF + o0];
                a0.x += p * hval.x; a0.y += p * hval.y; a0.z += p * hval.z; a0.w += p * hval.w;
            }
            int o1 = o0 - 1;
            if ((unsigned)o1 <= 64u) {
                float p = ps[(ob + 1) * NOFF + o1];
                a1.x += p * hval.x; a1.y += p * hval.y; a1.z += p * hval.z; a1.w += p * hval.w;
            }
        }
#pragma unroll
        for (int r = 0; r < 2; ++r) {
            float4 a = r ? a1 : a0;
            float4 vv = *(const float4*)(ks + (WH + ob + r) * 68 + ci * 4);
            float4 o;
            o.x = 0.9f * a.x + 0.1f * vv.x;
            o.y = 0.9f * a.y + 0.1f * vv.y;
            o.z = 0.9f * a.z + 0.1f * vv.z;
            o.w = 0.9f * a.w + 0.1f * vv.w;
            *(float4*)(hA + (size_t)(i0 + ob + r) * E_DIM + h * 64 + ci * 4) = o;
        }
    }
}

// ---------------------------------------------------------------------------
// diffuse3m: THREE diffusion steps via banded MFMA (extends R10's verified
// diffuse2m). block = 64 out rows x 64 cols (one head), 512 thr (8 waves).
//   in[256 rows] -> mid1[192] -> mid2[128] -> out[64]
// mid2T overlays inT (dead after s1). All fb reads stay within staged rows;
// off-band fa == exact 0 -> halo invariant preserved.
// LDS: inT 33792 + m1T 25600 + ps 25344 = 84.7 KB -> 1 block/CU, 8 waves.
// ---------------------------------------------------------------------------
__global__ __launch_bounds__(512)
void diffuse3m(const float* __restrict__ hin, const float* __restrict__ v,
               const float* __restrict__ P, float* __restrict__ hout)
{
    __shared__ unsigned short inT[64 * 264];  // [col][in-row 0..255]; later m2T
    __shared__ unsigned short m1T[64 * 200];  // [col][mid1-row 0..191]
    __shared__ unsigned short ps[192 * 66];   // [row rk1][off 0..64] bf16
    unsigned short* m2T = inT;                // [col][mid2-row 0..127] stride 136
    const int i0 = blockIdx.x * 64;
    const int h  = blockIdx.y;
    const int c0 = h * 64;
    const int tid  = threadIdx.x;
    const int lane = tid & 63, wave = tid >> 6;
    const int quad = lane >> 4, l16 = lane & 15;

    // stage inT: rows [i0-96, i0+160), row-pairs -> u32 writes
    for (int e = tid; e < 128 * 16; e += 512) {
        int rp = (e >> 4) * 2, c4 = (e & 15) * 4;
        int ja = min(max(i0 - 96 + rp,     0), S_LEN - 1);
        int jb = min(max(i0 - 96 + rp + 1, 0), S_LEN - 1);
        float4 ha = *(const float4*)(hin + (size_t)ja * E_DIM + c0 + c4);
        float4 hb = *(const float4*)(hin + (size_t)jb * E_DIM + c0 + c4);
        *(unsigned*)(inT + (c4 + 0) * 264 + rp) = pk2(ha.x, hb.x);
        *(unsigned*)(inT + (c4 + 1) * 264 + rp) = pk2(ha.y, hb.y);
        *(unsigned*)(inT + (c4 + 2) * 264 + rp) = pk2(ha.z, hb.z);
        *(unsigned*)(inT + (c4 + 3) * 264 + rp) = pk2(ha.w, hb.w);
    }
    // stage ps: P rows [i0-64, i0+128)
    for (int e = tid; e < 192 * 33; e += 512) {
        int mr = e / 33, t = e - mr * 33;
        int jc = min(max(i0 - 64 + mr, 0), S_LEN - 1);
        const float* pr = P + (size_t)jc * PROW + h * NOFF;
        if (t < 32)
            *(unsigned*)(ps + mr * 66 + t * 2) = pk2(pr[t * 2], pr[t * 2 + 1]);
        else
            ps[mr * 66 + 64] = f2bf(pr[64]);
    }
    __syncthreads();

    // ---- s1: mid1 rows (rk1 0..191). 24 units (12 m-tiles x 2 n-halves).
#pragma unroll
    for (int uu = 0; uu < 3; ++uu) {
        int u = wave + uu * 8;
        int mtb = (u >> 1) * 16;
        int ntb = (u & 1) * 32;
        f32x4 a0 = {0.f,0.f,0.f,0.f}, a1 = a0;
        int ks0 = mtb >> 5;
        const int m = mtb + l16;
#pragma unroll
        for (int t = 0; t < 3; ++t) {
            int k0q = (ks0 + t) * 32 + quad * 8;
            short8 fa;
#pragma unroll
            for (int j = 0; j < 8; ++j) {
                int idx = k0q + j - m;
                int idc = min(max(idx, 0), 64);
                unsigned short pv = ps[m * 66 + idc];
                fa[j] = ((unsigned)idx <= 64u) ? (short)pv : (short)0;
            }
            short8 fb0 = *(const short8*)(inT + (ntb + l16) * 264 + k0q);
            short8 fb1 = *(const short8*)(inT + (ntb + 16 + l16) * 264 + k0q);
            a0 = __builtin_amdgcn_mfma_f32_16x16x32_bf16(fa, fb0, a0, 0, 0, 0);
            a1 = __builtin_amdgcn_mfma_f32_16x16x32_bf16(fa, fb1, a1, 0, 0, 0);
        }
#pragma unroll
        for (int nt = 0; nt < 2; ++nt) {
            f32x4 a = nt ? a1 : a0;
            int n = ntb + nt * 16 + l16;
            float o[4];
#pragma unroll
            for (int r = 0; r < 4; ++r) {
                int gm = min(max(i0 - 64 + mtb + quad * 4 + r, 0), S_LEN - 1);
                o[r] = 0.9f * a[r] + 0.1f * v[(size_t)gm * E_DIM + c0 + n];
            }
            *(unsigned*)(m1T + n * 200 + mtb + quad * 4)     = pk2(o[0], o[1]);
            *(unsigned*)(m1T + n * 200 + mtb + quad * 4 + 2) = pk2(o[2], o[3]);
        }
    }
    __syncthreads();

    // ---- s2: mid2 rows (rk2 0..127), source m1T, P row rk2+32. 16 units.
    // Writes m2T which overlays inT (inT dead after s1).
#pragma unroll
    for (int uu = 0; uu < 2; ++uu) {
        int u = wave + uu * 8;
        int mtb = (u >> 1) * 16;
        int ntb = (u & 1) * 32;
        f32x4 a0 = {0.f,0.f,0.f,0.f}, a1 = a0;
        int ks0 = mtb >> 5;
        const int m = mtb + l16;
#pragma unroll
        for (int t = 0; t < 3; ++t) {
            int k0q = (ks0 + t) * 32 + quad * 8;
            short8 fa;
#pragma unroll
            for (int j = 0; j < 8; ++j) {
                int idx = k0q + j - m;
                int idc = min(max(idx, 0), 64);
                unsigned short pv = ps[(m + 32) * 66 + idc];
                fa[j] = ((unsigned)idx <= 64u) ? (short)pv : (short)0;
            }
            short8 fb0 = *(const short8*)(m1T + (ntb + l16) * 200 + k0q);
            short8 fb1 = *(const short8*)(m1T + (ntb + 16 + l16) * 200 + k0q);
            a0 = __builtin_amdgcn_mfma_f32_16x16x32_bf16(fa, fb0, a0, 0, 0, 0);
            a1 = __builtin_amdgcn_mfma_f32_16x16x32_bf16(fa, fb1, a1, 0, 0, 0);
        }
        __syncthreads();   // uniform across waves; orders m2T writes vs any
                           // straggling inT reads (defensive -- inT is dead)
#pragma unroll
        for (int nt = 0; nt < 2; ++nt) {
            f32x4 a = nt ? a1 : a0;
            int n = ntb + nt * 16 + l16;
            float o[4];
#pragma unroll
            for (int r = 0; r < 4; ++r) {
                int gm = min(max(i0 - 32 + mtb + quad * 4 + r, 0), S_LEN - 1);
                o[r] = 0.9f * a[r] + 0.1f * v[(size_t)gm * E_DIM + c0 + n];
            }
            *(unsigned*)(m2T + n * 136 + mtb + quad * 4)     = pk2(o[0], o[1]);
            *(unsigned*)(m2T + n * 136 + mtb + quad * 4 + 2) = pk2(o[2], o[3]);
        }
    }
    __syncthreads();

    // ---- s3: out rows (rk3 0..63), source m2T, P row rk3+64. 8 units.
    {
        int u = wave;
        int mtb = (u >> 1) * 16;
        int ntb = (u & 1) * 32;
        f32x4 a0 = {0.f,0.f,0.f,0.f}, a1 = a0;
        int ks0 = mtb >> 5;
        const int m = mtb + l16;
#pragma unroll
        for (int t = 0; t < 3; ++t) {
            int k0q = (ks0 + t) * 32 + quad * 8;
            short8 fa;
#pragma unroll
            for (int j = 0; j < 8; ++j) {
                int idx = k0q + j - m;
                int idc = min(max(idx, 0), 64);
                unsigned short pv = ps[(m + 64) * 66 + idc];
                fa[j] = ((unsigned)idx <= 64u) ? (short)pv : (short)0;
            }
            short8 fb0 = *(const short8*)(m2T + (ntb + l16) * 136 + k0q);
            short8 fb1 = *(const short8*)(m2T + (ntb + 16 + l16) * 136 + k0q);
            a0 = __builtin_amdgcn_mfma_f32_16x16x32_bf16(fa, fb0, a0, 0, 0, 0);
            a1 = __builtin_amdgcn_mfma_f32_16x16x32_bf16(fa, fb1, a1, 0, 0, 0);
        }
#pragma unroll
        for (int nt = 0; nt < 2; ++nt) {
            f32x4 a = nt ? a1 : a0;
            int n = ntb + nt * 16 + l16;
#pragma unroll
            for (int r = 0; r < 4; ++r) {
                int gm = i0 + mtb + quad * 4 + r;   // always in range
                size_t base = (size_t)gm * E_DIM + c0 + n;
                hout[base] = 0.9f * a[r] + 0.1f * v[base];
            }
        }
    }
}

// ---------------------------------------------------------------------------
// oln3: diffusion step 5 (banded MFMA, waves 0-1) + h@Wo + bo + x + LayerNorm.
// Block = 16 rows x 512 cols, 512 threads, 128 blocks. LDS ~66 KB -> 2/CU.
// FIX (R12): h4T tail rows [80,96) are read by fb (k-window = 3 chunks = 96
// rows) but were never staged -> uninitialized LDS decoded as bf16 NaN/Inf,
// and MFMA propagates 0*NaN=NaN. Zero them once; they are never overwritten.
// ---------------------------------------------------------------------------
__global__ __launch_bounds__(512)
void oln3(const float* __restrict__ h4, const float* __restrict__ v,
          const float* __restrict__ P, const float* __restrict__ Wo,
          const float* __restrict__ bo, const float* __restrict__ x,
          const float* __restrict__ g, const float* __restrict__ lb,
          float* __restrict__ out)
{
    __shared__ unsigned short As[16 * 40];      // 1280 B
    __shared__ unsigned short Bs[512 * 40];     // 40960 B
    __shared__ unsigned short h4T[32 * 96];     // 6144 B  [col][row 0..95]
    __shared__ unsigned short ps16[16 * 528];   // 16896 B [m][head*65+off]
    __shared__ float rsum[8][16], rsq[8][16];   // 1024 B
    const int tid = threadIdx.x;
    const int lane = tid & 63, wave = tid >> 6;
    const int quad = lane >> 4, l16 = lane & 15;
    const int m0 = blockIdx.x * 16;
    const int n = tid;

    // FIX: zero un-staged h4T tail rows [80,96) (32 cols x 16 rows = 512 u16).
    {
        int col = tid >> 4, r = tid & 15;
        h4T[col * 96 + 80 + r] = 0;
    }
    // stage P rows m0..m0+16 (all heads) once, bf16
    for (int e = tid; e < 16 * 260; e += 512) {
        int mr = e / 260, t = e - mr * 260;
        const float* pr = P + (size_t)(m0 + mr) * PROW;
        *(unsigned*)(ps16 + mr * 528 + t * 2) = pk2(pr[t * 2], pr[t * 2 + 1]);
    }

    f32x4 acc[4];
#pragma unroll
    for (int t = 0; t < 4; ++t) acc[t] = (f32x4){0.f,0.f,0.f,0.f};

    for (int kk = 0; kk < E_DIM; kk += 32) {
        const int hd = kk >> 6;
        // global loads pre-barrier
        float4 hv0, hv1;
        {
            int r = tid >> 3, c4 = (tid & 7) * 4;
            int jc = min(max(m0 - 32 + r, 0), S_LEN - 1);
            hv0 = *(const float4*)(h4 + (size_t)jc * E_DIM + kk + c4);
        }
        if (tid < 128) {
            int e = tid + 512;
            int r = e >> 3, c4 = (e & 7) * 4;
            int jc = min(max(m0 - 32 + r, 0), S_LEN - 1);
            hv1 = *(const float4*)(h4 + (size_t)jc * E_DIM + kk + c4);
        }
        float bcol[32];
#pragma unroll
        for (int j = 0; j < 32; ++j)
            bcol[j] = Wo[(size_t)(kk + j) * E_DIM + n];
        __syncthreads();   // prior iter's As/Bs/h4T reads complete
        {
            int r = tid >> 3, c4 = (tid & 7) * 4;
            h4T[(c4 + 0) * 96 + r] = f2bf(hv0.x);
            h4T[(c4 + 1) * 96 + r] = f2bf(hv0.y);
            h4T[(c4 + 2) * 96 + r] = f2bf(hv0.z);
            h4T[(c4 + 3) * 96 + r] = f2bf(hv0.w);
        }
        if (tid < 128) {
            int e = tid + 512;
            int r = e >> 3, c4 = (e & 7) * 4;
            h4T[(c4 + 0) * 96 + r] = f2bf(hv1.x);
            h4T[(c4 + 1) * 96 + r] = f2bf(hv1.y);
            h4T[(c4 + 2) * 96 + r] = f2bf(hv1.z);
            h4T[(c4 + 3) * 96 + r] = f2bf(hv1.w);
        }
#pragma unroll
        for (int t = 0; t < 4; ++t) {
            uint4 bp;
            bp.x = pk2(bcol[t*8+0], bcol[t*8+1]); bp.y = pk2(bcol[t*8+2], bcol[t*8+3]);
            bp.z = pk2(bcol[t*8+4], bcol[t*8+5]); bp.w = pk2(bcol[t*8+6], bcol[t*8+7]);
            *(uint4*)(Bs + n * 40 + t * 8) = bp;
        }
        __syncthreads();

        // band build (step 5): waves 0-1 produce As[16 m][32 c] = 0.9*P@h4 + 0.1*v
        if (wave < 2) {
            const int ntb = wave * 16;
            f32x4 ba = {0.f,0.f,0.f,0.f};
#pragma unroll
            for (int t = 0; t < 3; ++t) {
                int k0q = t * 32 + quad * 8;
                short8 fa;
#pragma unroll
                for (int j = 0; j < 8; ++j) {
                    int idx = k0q + j - l16;          // row m = l16
                    int idc = min(max(idx, 0), 64);
                    unsigned short pv = ps16[l16 * 528 + hd * NOFF + idc];
                    fa[j] = ((unsigned)idx <= 64u) ? (short)pv : (short)0;
                }
                short8 fb = *(const short8*)(h4T + (ntb + l16) * 96 + k0q);
                ba = __builtin_amdgcn_mfma_f32_16x16x32_bf16(fa, fb, ba, 0, 0, 0);
            }
#pragma unroll
            for (int r = 0; r < 4; ++r) {
                int m = quad * 4 + r;
                float vv = v[(size_t)(m0 + m) * E_DIM + kk + ntb + l16];
                As[m * 40 + ntb + l16] = f2bf(0.9f * ba[r] + 0.1f * vv);
            }
        }
        __syncthreads();

        short8 fa = *(const short8*)(As + l16 * 40 + quad * 8);
#pragma unroll
        for (int nt = 0; nt < 4; ++nt) {
            short8 fb = *(const short8*)(Bs + (wave * 64 + nt * 16 + l16) * 40 + quad * 8);
            acc[nt] = __builtin_amdgcn_mfma_f32_16x16x32_bf16(fa, fb, acc[nt], 0, 0, 0);
        }
    }

    // epilogue: bias + resid, LN (proven R4/R6/R8)
    float s[4] = {0.f,0.f,0.f,0.f}, s2[4] = {0.f,0.f,0.f,0.f};
#pragma unroll
    for (int nt = 0; nt < 4; ++nt) {
        int nc = wave * 64 + nt * 16 + l16;
        float bv = bo[nc];
#pragma unroll
        for (int r = 0; r < 4; ++r) {
            int m = m0 + quad * 4 + r;
            float vl = acc[nt][r] + bv + x[(size_t)m * E_DIM + nc];
            acc[nt][r] = vl;
            s[r] += vl; s2[r] += vl * vl;
        }
    }
#pragma unroll
    for (int o = 1; o < 16; o <<= 1) {
#pragma unroll
        for (int r = 0; r < 4; ++r) {
            s[r]  += __shfl_xor(s[r], o, 64);
            s2[r] += __shfl_xor(s2[r], o, 64);
        }
    }
    if (l16 == 0) {
#pragma unroll
        for (int r = 0; r < 4; ++r) {
            rsum[wave][quad * 4 + r] = s[r];
            rsq[wave][quad * 4 + r]  = s2[r];
        }
    }
    __syncthreads();
    float mu[4], rs[4];
#pragma unroll
    for (int r = 0; r < 4; ++r) {
        int rl = quad * 4 + r;
        float tot = 0.f, tot2 = 0.f;
#pragma unroll
        for (int w = 0; w < 8; ++w) { tot += rsum[w][rl]; tot2 += rsq[w][rl]; }
        float m_ = tot * (1.f / 512.f);
        float var = tot2 * (1.f / 512.f) - m_ * m_;
        mu[r] = m_; rs[r] = rsqrtf(var + 1e-12f);
    }
#pragma unroll
    for (int nt = 0; nt < 4; ++nt) {
        int nc = wave * 64 + nt * 16 + l16;
        float gv = g[nc], bbv = lb[nc];
#pragma unroll
        for (int r = 0; r < 4; ++r) {
            int m = m0 + quad * 4 + r;
            out[(size_t)m * E_DIM + nc] = (acc[nt][r] - mu[r]) * rs[r] * gv + bbv;
        }
    }
}

// ---------------------------------------------------------------------------
extern "C" void kernel_launch(void* const* d_in, const int* in_sizes, int n_in,
                              void* d_out, int out_size, void* d_ws, size_t ws_size,
                              hipStream_t stream)
{
    const float* x     = (const float*)d_in[0];
    const float* amask = (const float*)d_in[1];
    const float* Wq = (const float*)d_in[4];
    const float* bq = (const float*)d_in[5];
    const float* Wk = (const float*)d_in[6];
    const float* bk = (const float*)d_in[7];
    const float* Wv = (const float*)d_in[8];
    const float* bv = (const float*)d_in[9];
    const float* Wo = (const float*)d_in[10];
    const float* bo = (const float*)d_in[11];
    const float* lng = (const float*)d_in[12];
    const float* lnb = (const float*)d_in[13];
    float* out = (float*)d_out;

    float* ws = (float*)d_ws;
    float* q  = ws;
    float* k  = ws + (size_t)NE;
    float* v  = ws + (size_t)2 * NE;
    float* P  = ws + (size_t)3 * NE;
    float* hA = ws + (size_t)3 * NE + PN;
    float* hB = hA + (size_t)NE;

    qkv_gemm<<<dim3(8, 32, 3), 256, 0, stream>>>(x, Wq, bq, Wk, bk, Wv, bv, q, k, v);

    scores_d1<<<dim3(64, 8), 256, 0, stream>>>(q, k, v, amask, P, hA);   // P + step 1

    diffuse3m<<<dim3(32, 8), 512, 0, stream>>>(hA, v, P, hB);            // steps 2-4

    oln3<<<128, 512, 0, stream>>>(hB, v, P, Wo, bo, x, lng, lnb, out);   // step 5 + GEMM + LN
}